// Round 3
// baseline (444.824 us; speedup 1.0000x reference)
//
#include <hip/hip_runtime.h>
#include <hip/hip_bf16.h>

#define NNET 24
#define WD 64

__device__ __forceinline__ float fast_tanh(float x) {
    float ax = __builtin_fabsf(x);
    float e  = __builtin_amdgcn_exp2f(ax * 2.885390081777927f);   // exp(2|x|)
    float r  = __builtin_amdgcn_rcpf(e + 1.0f);
    float t  = 1.0f - 2.0f * r;
    return __builtin_copysignf(t, x);
}

// ------------- Kernel A: full-fp32 3-layer MLP, one thread = one (row, net) --
__global__ __launch_bounds__(256)
void mlp_fp32_kernel(const float* __restrict__ x,
                     const float* __restrict__ W1,
                     const float* __restrict__ b1,
                     const float* __restrict__ W2,
                     const float* __restrict__ b2,
                     const float* __restrict__ W3,
                     float* __restrict__ subout,   // mode1: subT [24][N]; mode0: sub [N][24]
                     int N, int mode)
{
    const int t   = threadIdx.x;
    const int net = blockIdx.y;
    const int row = blockIdx.x * 256 + t;

    // block-uniform weight pointers (compiler promotes these loads to SMEM)
    const float* __restrict__ W1n = W1 + net * 128;
    const float* __restrict__ b1n = b1 + net * 64;
    const float* __restrict__ W2n = W2 + net * 4096;
    const float* __restrict__ b2n = b2 + net * 64;
    const float* __restrict__ W3n = W3 + net * 64;

    const float2 xv = reinterpret_cast<const float2*>(x)[row];
    const float x0 = xv.x, x1 = xv.y;

    // ---- layer 1 (fp32) + tanh, h1 kept in registers ----
    float h1r[WD];
#pragma unroll
    for (int w = 0; w < WD; ++w) {
        float pre = x0 * W1n[2 * w] + x1 * W1n[2 * w + 1] + b1n[w];
        h1r[w] = fast_tanh(pre);
    }

    // ---- layer 2 (fp32 VALU) + tanh + layer 3 dot, fused over v ----
    float subv = 0.0f;
    for (int v = 0; v < WD; ++v) {
        const float* __restrict__ w2row = W2n + v * 64;
        float a = b2n[v];
#pragma unroll
        for (int w = 0; w < WD; ++w)
            a = fmaf(h1r[w], w2row[w], a);
        subv = fmaf(fast_tanh(a), W3n[v], subv);
    }

    if (mode) {
        subout[(size_t)net * N + row] = subv;
    } else {
        subout[(size_t)row * NNET + net] = subv;
    }
}

// ---------------- Kernel B: per-sample softmin free-energy + sub transpose ----
__global__ __launch_bounds__(256)
void finalize_kernel(const float* __restrict__ subsrc,  // mode1: subT [24][N]; mode0: sub [N][24]
                     const float* __restrict__ x,
                     float* __restrict__ outv,
                     float* __restrict__ subdst,        // sub [N][24] (written only in mode 1)
                     int N, int mode)
{
    const int t  = threadIdx.x;
    const int m0 = blockIdx.x * 256;
    const int n  = m0 + t;

    float v[NNET];
    if (mode) {
#pragma unroll
        for (int k = 0; k < NNET; ++k) v[k] = subsrc[(size_t)k * N + n];
    } else {
#pragma unroll
        for (int k = 0; k < NNET; ++k) v[k] = subsrc[(size_t)n * NNET + k];
    }

    __shared__ float s[256 * 25];
    if (mode) {
#pragma unroll
        for (int k = 0; k < NNET; ++k) s[t * 25 + k] = v[k];
        __syncthreads();
        const size_t base = (size_t)m0 * NNET;
#pragma unroll
        for (int i = 0; i < NNET; ++i) {
            int f = i * 256 + t;
            int r = f / NNET;
            int col = f - r * NNET;
            subdst[base + f] = s[r * 25 + col];
        }
    }

    const float T = fmaxf(x[2 * n + 1], 0.1f);
    const float kbT = 0.1f * T;

    // np-order-faithful: net2**2, then T*net2sq, then subtract, then true division
    float vals[12];
#pragma unroll
    for (int j = 0; j < 12; ++j) {
        float n2   = v[2 * j + 1];
        float n2sq = n2 * n2;
        float tn2  = T * n2sq;
        vals[j] = v[2 * j] - tn2;
    }

    float ee[12];
    float sum = 0.f;
#pragma unroll
    for (int j = 0; j < 12; ++j) {
        float ex = fminf((-vals[j]) / kbT, 10.0f);
        float l  = __builtin_amdgcn_exp2f(ex * 1.4426950408889634f);
        ee[j] = l;
        sum += l;
    }
    sum += 1e-9f;
    const float rs = 1.0f / sum;
    float wvs = 0.f, wlp = 0.f;
#pragma unroll
    for (int j = 0; j < 12; ++j) {
        float w = ee[j] * rs;
        wvs = fmaf(w, vals[j], wvs);
        wlp = fmaf(w, __builtin_amdgcn_logf(w + 1e-9f) * 0.6931471805599453f, wlp);
    }
    outv[n] = fmaf(kbT, wlp, wvs);
}

extern "C" void kernel_launch(void* const* d_in, const int* in_sizes, int n_in,
                              void* d_out, int out_size, void* d_ws, size_t ws_size,
                              hipStream_t stream) {
    const float* x  = (const float*)d_in[0];
    const float* W1 = (const float*)d_in[1];
    const float* b1 = (const float*)d_in[2];
    const float* W2 = (const float*)d_in[3];
    const float* b2 = (const float*)d_in[4];
    const float* W3 = (const float*)d_in[5];

    const int N = in_sizes[0] / 2;      // 131072
    float* outv   = (float*)d_out;
    float* subdst = outv + N;           // sub (N,24) region of d_out

    const size_t need = (size_t)NNET * N * sizeof(float);
    const int mode = (ws_size >= need) ? 1 : 0;
    float* subT = (float*)d_ws;
    float* asub = mode ? subT : subdst;

    dim3 gA(N / 256, NNET);
    mlp_fp32_kernel<<<gA, 256, 0, stream>>>(x, W1, b1, W2, b2, W3, asub, N, mode);

    finalize_kernel<<<N / 256, 256, 0, stream>>>(mode ? (const float*)subT : (const float*)subdst,
                                                 x, outv, subdst, N, mode);
}

// Round 4
// 237.562 us; speedup vs baseline: 1.8725x; 1.8725x over previous
//
#include <hip/hip_runtime.h>
#include <hip/hip_bf16.h>

#define NNET 24
#define WD 64
#define MT 256   // rows per block (kernel A)

typedef __attribute__((ext_vector_type(8))) _Float16 f16x8;
typedef __attribute__((ext_vector_type(4))) float f32x4;
typedef __attribute__((ext_vector_type(4))) unsigned int u32x4;

__device__ __forceinline__ float fast_tanh(float x) {
    float ax = __builtin_fabsf(x);
    float e  = __builtin_amdgcn_exp2f(ax * 2.885390081777927f);   // exp(2|x|)
    float r  = __builtin_amdgcn_rcpf(e + 1.0f);
    float t  = 1.0f - 2.0f * r;
    return __builtin_copysignf(t, x);
}

__device__ __forceinline__ unsigned short h2u(_Float16 h) {
    return __builtin_bit_cast(unsigned short, h);
}

// ---- Kernel A: 3-layer MLP; layer 2 = MFMA f16 with full Ootomo hi/lo split
__global__ __launch_bounds__(256, 2)
void mlp_mfma_kernel(const float* __restrict__ x,
                     const float* __restrict__ W1,
                     const float* __restrict__ b1,
                     const float* __restrict__ W2,
                     const float* __restrict__ b2,
                     const float* __restrict__ W3,
                     float* __restrict__ subout,   // mode1: subT [24][N]; mode0: sub [N][24]
                     int N, int mode)
{
    const int t    = threadIdx.x;
    const int net  = blockIdx.y;
    const int m0   = blockIdx.x * MT;
    const int lane = t & 63;
    const int wv   = t >> 6;         // wave 0..3
    const int c    = lane & 15;      // col/row-in-frag
    const int q    = lane >> 4;      // 0..3

    __shared__ float w1s[WD * 2];
    __shared__ float b1s[WD];
    __shared__ float b2s[WD];
    __shared__ float w3s[WD];
    __shared__ __align__(16) unsigned short h1hi[MT][72];   // f16 hi bits, stride 72 (144B)
    __shared__ __align__(16) unsigned short h1lo[MT][72];   // f16 lo bits (×2^11)

    // ---- stage small weights to LDS ----
    if (t < 128) w1s[t] = W1[net * 128 + t];
    if (t < 64) {
        b1s[t] = b1[net * 64 + t];
        b2s[t] = b2[net * 64 + t];
        w3s[t] = W3[net * 64 + t];
    }

    __syncthreads();   // w1s/b1s ready

    // ---- layer 1 (fp32) + tanh; split each h1 into f16 hi + scaled f16 lo ----
    {
        const float2 xv = reinterpret_cast<const float2*>(x)[m0 + t];
#pragma unroll
        for (int w8 = 0; w8 < 8; ++w8) {
            unsigned int hpk[4], lpk[4];
#pragma unroll
            for (int jj = 0; jj < 4; ++jj) {
                const int w0 = w8 * 8 + jj * 2;
                float a0 = fmaf(w1s[w0 * 2 + 0], xv.x, fmaf(w1s[w0 * 2 + 1], xv.y, b1s[w0 + 0]));
                float a1 = fmaf(w1s[w0 * 2 + 2], xv.x, fmaf(w1s[w0 * 2 + 3], xv.y, b1s[w0 + 1]));
                float t0 = fast_tanh(a0);
                float t1 = fast_tanh(a1);
                _Float16 h0 = (_Float16)t0;
                _Float16 h1v = (_Float16)t1;
                _Float16 l0 = (_Float16)((t0 - (float)h0) * 2048.0f);
                _Float16 l1 = (_Float16)((t1 - (float)h1v) * 2048.0f);
                hpk[jj] = (unsigned int)h2u(h0) | ((unsigned int)h2u(h1v) << 16);
                lpk[jj] = (unsigned int)h2u(l0) | ((unsigned int)h2u(l1) << 16);
            }
            *reinterpret_cast<u32x4*>(&h1hi[t][w8 * 8]) = (u32x4){hpk[0], hpk[1], hpk[2], hpk[3]};
            *reinterpret_cast<u32x4*>(&h1lo[t][w8 * 8]) = (u32x4){lpk[0], lpk[1], lpk[2], lpk[3]};
        }
    }

    __syncthreads();   // h1 ready

    // ---- B fragments (W2^T) global -> regs, f16 hi + scaled f16 lo ----
    // B[k=w][col=v] = W2[net][v][w]; lane l, elem j: k = kk*32 + q*8 + j, col = nf*16 + c
    f16x8 bhi[4][2], blo[4][2];
    const float* W2n = W2 + (size_t)net * 4096;
#pragma unroll
    for (int nf = 0; nf < 4; ++nf) {
#pragma unroll
        for (int kk = 0; kk < 2; ++kk) {
            const float* p = W2n + (nf * 16 + c) * 64 + kk * 32 + q * 8;
            float4 f0 = *reinterpret_cast<const float4*>(p);
            float4 f1 = *reinterpret_cast<const float4*>(p + 4);
            float w[8] = {f0.x, f0.y, f0.z, f0.w, f1.x, f1.y, f1.z, f1.w};
            f16x8 hh, ll;
#pragma unroll
            for (int j = 0; j < 8; ++j) {
                _Float16 h = (_Float16)w[j];
                hh[j] = h;
                ll[j] = (_Float16)((w[j] - (float)h) * 2048.0f);
            }
            bhi[nf][kk] = hh;
            blo[nf][kk] = ll;
        }
    }

    // epilogue constants
    float w3v[4], b2v[4];
#pragma unroll
    for (int nf = 0; nf < 4; ++nf) {
        w3v[nf] = w3s[nf * 16 + c];
        b2v[nf] = b2s[nf * 16 + c];
    }

    // ---- layer 2 via MFMA, 3-term split: hi*hi + (hi*lo + lo*hi)*2^-11 ----
#pragma unroll
    for (int mf = 0; mf < 4; ++mf) {
        f32x4 accH[4], accX1[4], accX2[4];
#pragma unroll
        for (int nf = 0; nf < 4; ++nf) {
            accH[nf]  = (f32x4){0.f, 0.f, 0.f, 0.f};
            accX1[nf] = (f32x4){0.f, 0.f, 0.f, 0.f};
            accX2[nf] = (f32x4){0.f, 0.f, 0.f, 0.f};
        }
#pragma unroll
        for (int kk = 0; kk < 2; ++kk) {
            f16x8 ahi = *reinterpret_cast<const f16x8*>(&h1hi[wv * 64 + mf * 16 + c][kk * 32 + q * 8]);
            f16x8 alo = *reinterpret_cast<const f16x8*>(&h1lo[wv * 64 + mf * 16 + c][kk * 32 + q * 8]);
#pragma unroll
            for (int nf = 0; nf < 4; ++nf) {
                accH[nf]  = __builtin_amdgcn_mfma_f32_16x16x32_f16(ahi, bhi[nf][kk], accH[nf], 0, 0, 0);
                accX1[nf] = __builtin_amdgcn_mfma_f32_16x16x32_f16(ahi, blo[nf][kk], accX1[nf], 0, 0, 0);
                accX2[nf] = __builtin_amdgcn_mfma_f32_16x16x32_f16(alo, bhi[nf][kk], accX2[nf], 0, 0, 0);
            }
        }

        // ---- epilogue: recombine, +b2, tanh, dot W3, reduce over 16 cols ----
        float p0 = 0.f, p1 = 0.f, p2 = 0.f, p3 = 0.f;
#pragma unroll
        for (int nf = 0; nf < 4; ++nf) {
            float v0 = accH[nf][0] + (accX1[nf][0] + accX2[nf][0]) * 4.8828125e-4f + b2v[nf];
            float v1 = accH[nf][1] + (accX1[nf][1] + accX2[nf][1]) * 4.8828125e-4f + b2v[nf];
            float v2 = accH[nf][2] + (accX1[nf][2] + accX2[nf][2]) * 4.8828125e-4f + b2v[nf];
            float v3 = accH[nf][3] + (accX1[nf][3] + accX2[nf][3]) * 4.8828125e-4f + b2v[nf];
            p0 = fmaf(fast_tanh(v0), w3v[nf], p0);
            p1 = fmaf(fast_tanh(v1), w3v[nf], p1);
            p2 = fmaf(fast_tanh(v2), w3v[nf], p2);
            p3 = fmaf(fast_tanh(v3), w3v[nf], p3);
        }
#pragma unroll
        for (int off = 1; off <= 8; off <<= 1) {
            p0 += __shfl_xor(p0, off, 64);
            p1 += __shfl_xor(p1, off, 64);
            p2 += __shfl_xor(p2, off, 64);
            p3 += __shfl_xor(p3, off, 64);
        }
        if (c == 0) {
            const int r = m0 + wv * 64 + mf * 16 + q * 4;
            if (mode) {
                float* o = subout + (size_t)net * N + r;
                o[0] = p0; o[1] = p1; o[2] = p2; o[3] = p3;
            } else {
                subout[(size_t)(r + 0) * NNET + net] = p0;
                subout[(size_t)(r + 1) * NNET + net] = p1;
                subout[(size_t)(r + 2) * NNET + net] = p2;
                subout[(size_t)(r + 3) * NNET + net] = p3;
            }
        }
    }
}

// ---------------- Kernel B: per-sample softmin free-energy + sub transpose ----
__global__ __launch_bounds__(256)
void finalize_kernel(const float* __restrict__ subsrc,  // mode1: subT [24][N]; mode0: sub [N][24]
                     const float* __restrict__ x,
                     float* __restrict__ outv,
                     float* __restrict__ subdst,        // sub [N][24] (written only in mode 1)
                     int N, int mode)
{
    const int t  = threadIdx.x;
    const int m0 = blockIdx.x * 256;
    const int n  = m0 + t;

    float v[NNET];
    if (mode) {
#pragma unroll
        for (int k = 0; k < NNET; ++k) v[k] = subsrc[(size_t)k * N + n];
    } else {
#pragma unroll
        for (int k = 0; k < NNET; ++k) v[k] = subsrc[(size_t)n * NNET + k];
    }

    __shared__ float s[256 * 25];
    if (mode) {
#pragma unroll
        for (int k = 0; k < NNET; ++k) s[t * 25 + k] = v[k];
        __syncthreads();
        const size_t base = (size_t)m0 * NNET;
#pragma unroll
        for (int i = 0; i < NNET; ++i) {
            int f = i * 256 + t;
            int r = f / NNET;
            int col = f - r * NNET;
            subdst[base + f] = s[r * 25 + col];
        }
    }

    const float T = fmaxf(x[2 * n + 1], 0.1f);
    const float kbT = 0.1f * T;

    float vals[12];
#pragma unroll
    for (int j = 0; j < 12; ++j) {
        float n2   = v[2 * j + 1];
        float n2sq = n2 * n2;
        float tn2  = T * n2sq;
        vals[j] = v[2 * j] - tn2;
    }

    float ee[12];
    float sum = 0.f;
#pragma unroll
    for (int j = 0; j < 12; ++j) {
        float ex = fminf((-vals[j]) / kbT, 10.0f);
        float l  = __builtin_amdgcn_exp2f(ex * 1.4426950408889634f);
        ee[j] = l;
        sum += l;
    }
    sum += 1e-9f;
    const float rs = 1.0f / sum;
    float wvs = 0.f, wlp = 0.f;
#pragma unroll
    for (int j = 0; j < 12; ++j) {
        float w = ee[j] * rs;
        wvs = fmaf(w, vals[j], wvs);
        wlp = fmaf(w, __builtin_amdgcn_logf(w + 1e-9f) * 0.6931471805599453f, wlp);
    }
    outv[n] = fmaf(kbT, wlp, wvs);
}

extern "C" void kernel_launch(void* const* d_in, const int* in_sizes, int n_in,
                              void* d_out, int out_size, void* d_ws, size_t ws_size,
                              hipStream_t stream) {
    const float* x  = (const float*)d_in[0];
    const float* W1 = (const float*)d_in[1];
    const float* b1 = (const float*)d_in[2];
    const float* W2 = (const float*)d_in[3];
    const float* b2 = (const float*)d_in[4];
    const float* W3 = (const float*)d_in[5];

    const int N = in_sizes[0] / 2;      // 131072
    float* outv   = (float*)d_out;
    float* subdst = outv + N;           // sub (N,24) region of d_out

    const size_t need = (size_t)NNET * N * sizeof(float);
    const int mode = (ws_size >= need) ? 1 : 0;
    float* subT = (float*)d_ws;
    float* asub = mode ? subT : subdst;

    dim3 gA(N / MT, NNET);
    mlp_mfma_kernel<<<gA, 256, 0, stream>>>(x, W1, b1, W2, b2, W3, asub, N, mode);

    finalize_kernel<<<N / 256, 256, 0, stream>>>(mode ? (const float*)subT : (const float*)subdst,
                                                 x, outv, subdst, N, mode);
}